// Round 6
// baseline (48.817 us; speedup 1.0000x reference)
//
#include <hip/hip_runtime.h>
#include <math.h>

#define HW 256
#define NPTS (HW * HW)
#define NP4 (NPTS / 4)
#define NKPT 68
#define NBATCH 128
#define KB 4            // batches per block

typedef float f32x4 __attribute__((ext_vector_type(4)));

// ---------------------------------------------------------------------------
// Fused kernel. Phase 1: wave k (of 4) computes the similarity transform for
// batch b0+k — 64 lanes gather the 68 keypoints (lanes 0..3 take a second
// point), 17 scalars are shfl-reduced across the wave, lane 0 runs the 3x3
// Newton polar iteration (R = V U^T from SVD(H) == polar factor of H^T,
// scale-invariant) and writes [s*R | t] to LDS. Phase 2: streaming apply,
//   out[b,r,i] = sum_c (s*R)[r][c]*(Offset[b,c,i]*6 + mean[c,i]) + t[r].
// Transform work is redundant across the 64 x-blocks of a batch-group but
// fully overlapped with other blocks' streaming (all 2048 blocks resident),
// eliminating the separate tform dispatch + inter-kernel drain.
// ---------------------------------------------------------------------------
__global__ __launch_bounds__(256) void fused_rebuild_kernel(
    const float* __restrict__ Offset,   // (B,3,HW,HW) scalar view
    const float* __restrict__ Posmap,   // (B,3,HW,HW)
    const float* __restrict__ meanp,    // (3,HW,HW)
    const int*   __restrict__ uv,       // (68,2)
    const f32x4* __restrict__ Off4,     // (B,3,NP4) vector view
    const f32x4* __restrict__ mean4,    // (3,NP4)
    f32x4* __restrict__ out)            // (B,3,NP4)
{
    const int tid  = threadIdx.x;
    const int wv   = tid >> 6;          // 0..3 — wave handles batch b0+wv
    const int lane = tid & 63;
    const int b0   = blockIdx.y * KB;

    __shared__ float srt[12 * KB];

    // ---------------- Phase 1: per-wave transform estimation ----------------
    {
        const int b = b0 + wv;
        const float* ob = Offset + (size_t)b * 3 * NPTS;
        const float* pb = Posmap + (size_t)b * 3 * NPTS;

        // point A = keypoint `lane`; point B = keypoint 64+lane (lanes 0..3)
        float sA[3], dA[3], sB[3] = {0.f, 0.f, 0.f}, dB[3] = {0.f, 0.f, 0.f};
        {
            const int pix = uv[2 * lane] * HW + uv[2 * lane + 1];
#pragma unroll
            for (int c = 0; c < 3; ++c) {
                sA[c] = fmaf(ob[c * NPTS + pix], 6.0f, meanp[c * NPTS + pix]);
                dA[c] = pb[c * NPTS + pix];
            }
        }
        const bool has2 = lane < (NKPT - 64);
        if (has2) {
            const int kp = 64 + lane;
            const int pix = uv[2 * kp] * HW + uv[2 * kp + 1];
#pragma unroll
            for (int c = 0; c < 3; ++c) {
                sB[c] = fmaf(ob[c * NPTS + pix], 6.0f, meanp[c * NPTS + pix]);
                dB[c] = pb[c * NPTS + pix];
            }
        }

        // broadcast keypoint 0 (lane 0's point A) across the wave
        const float s0x = __shfl(sA[0], 0), s0y = __shfl(sA[1], 0), s0z = __shfl(sA[2], 0);
        const float d0x = __shfl(dA[0], 0), d0y = __shfl(dA[1], 0), d0z = __shfl(dA[2], 0);

        float vals[17];
        float dd1 = 0.f, dd2 = 0.f;
        if (lane > 0) {
            float dx = sA[0] - s0x, dy = sA[1] - s0y, dz = sA[2] - s0z;
            dd1 = sqrtf(dx * dx + dy * dy + dz * dz);
            dx = dA[0] - d0x; dy = dA[1] - d0y; dz = dA[2] - d0z;
            dd2 = sqrtf(dx * dx + dy * dy + dz * dz);
        }
        if (has2) {
            float dx = sB[0] - s0x, dy = sB[1] - s0y, dz = sB[2] - s0z;
            dd1 += sqrtf(dx * dx + dy * dy + dz * dz);
            dx = dB[0] - d0x; dy = dB[1] - d0y; dz = dB[2] - d0z;
            dd2 += sqrtf(dx * dx + dy * dy + dz * dz);
        }
        vals[0] = dd1;
        vals[1] = dd2;
#pragma unroll
        for (int c = 0; c < 3; ++c) {
            vals[2 + c] = sA[c] + sB[c];
            vals[5 + c] = dA[c] + dB[c];
        }
#pragma unroll
        for (int r = 0; r < 3; ++r)
#pragma unroll
            for (int c = 0; c < 3; ++c)
                vals[8 + r * 3 + c] = sA[r] * dA[c] + sB[r] * dB[c];

        // 64-lane butterfly-free reduce (shfl_down tree)
#pragma unroll
        for (int j = 0; j < 17; ++j) {
            float v = vals[j];
#pragma unroll
            for (int off = 32; off > 0; off >>= 1)
                v += __shfl_down(v, off);
            vals[j] = v;
        }

        if (lane == 0) {
            const float s = vals[1] / vals[0];
            const float invN = 1.0f / (float)NKPT;
            float mS[3], mD[3];
#pragma unroll
            for (int c = 0; c < 3; ++c) {
                mS[c] = vals[2 + c] * invN;
                mD[c] = vals[5 + c] * invN;
            }

            float X[3][3];   // X = H^T ; H[r][c] = sum - N*mS[r]*mD[c]
#pragma unroll
            for (int r = 0; r < 3; ++r)
#pragma unroll
                for (int c = 0; c < 3; ++c)
                    X[c][r] = vals[8 + r * 3 + c] - (float)NKPT * mS[r] * mD[c];

            float nf = 0.f;
#pragma unroll
            for (int r = 0; r < 3; ++r)
#pragma unroll
                for (int c = 0; c < 3; ++c)
                    nf += X[r][c] * X[r][c];
            nf = rsqrtf(nf);
#pragma unroll
            for (int r = 0; r < 3; ++r)
#pragma unroll
                for (int c = 0; c < 3; ++c)
                    X[r][c] *= nf;

            for (int it = 0; it < 16; ++it) {
                float C[3][3];
                C[0][0] = X[1][1] * X[2][2] - X[1][2] * X[2][1];
                C[0][1] = X[1][2] * X[2][0] - X[1][0] * X[2][2];
                C[0][2] = X[1][0] * X[2][1] - X[1][1] * X[2][0];
                C[1][0] = X[2][1] * X[0][2] - X[2][2] * X[0][1];
                C[1][1] = X[2][2] * X[0][0] - X[2][0] * X[0][2];
                C[1][2] = X[2][0] * X[0][1] - X[2][1] * X[0][0];
                C[2][0] = X[0][1] * X[1][2] - X[0][2] * X[1][1];
                C[2][1] = X[0][2] * X[1][0] - X[0][0] * X[1][2];
                C[2][2] = X[0][0] * X[1][1] - X[0][1] * X[1][0];
                const float det = X[0][0] * C[0][0] + X[0][1] * C[0][1] + X[0][2] * C[0][2];
                const float inv = 0.5f / det;
#pragma unroll
                for (int r = 0; r < 3; ++r)
#pragma unroll
                    for (int c = 0; c < 3; ++c)
                        X[r][c] = 0.5f * X[r][c] + C[r][c] * inv;
            }

            float* o = &srt[12 * wv];
#pragma unroll
            for (int r = 0; r < 3; ++r) {
#pragma unroll
                for (int c = 0; c < 3; ++c)
                    o[r * 3 + c] = s * X[r][c];
                o[9 + r] = mD[r] - s * (X[r][0] * mS[0] + X[r][1] * mS[1] + X[r][2] * mS[2]);
            }
        }
    }
    __syncthreads();

    // ---------------- Phase 2: streaming apply ----------------
    const int g = blockIdx.x * blockDim.x + tid;   // pixel-group index

    const f32x4 mx = mean4[0 * NP4 + g];
    const f32x4 my = mean4[1 * NP4 + g];
    const f32x4 mz = mean4[2 * NP4 + g];

#pragma unroll
    for (int k = 0; k < KB; ++k) {
        const float* R = &srt[12 * k];
        const float R00 = R[0], R01 = R[1], R02 = R[2];
        const float R10 = R[3], R11 = R[4], R12 = R[5];
        const float R20 = R[6], R21 = R[7], R22 = R[8];
        const float t0 = R[9], t1 = R[10], t2 = R[11];

        const size_t base = (size_t)(b0 + k) * 3 * NP4;
        const f32x4 ox = Off4[base + 0 * NP4 + g];
        const f32x4 oy = Off4[base + 1 * NP4 + g];
        const f32x4 oz = Off4[base + 2 * NP4 + g];

        f32x4 r0, r1, r2;
#pragma unroll
        for (int j = 0; j < 4; ++j) {
            const float px = fmaf(ox[j], 6.0f, mx[j]);
            const float py = fmaf(oy[j], 6.0f, my[j]);
            const float pz = fmaf(oz[j], 6.0f, mz[j]);
            r0[j] = fmaf(R00, px, fmaf(R01, py, fmaf(R02, pz, t0)));
            r1[j] = fmaf(R10, px, fmaf(R11, py, fmaf(R12, pz, t1)));
            r2[j] = fmaf(R20, px, fmaf(R21, py, fmaf(R22, pz, t2)));
        }

        out[base + 0 * NP4 + g] = r0;
        out[base + 1 * NP4 + g] = r1;
        out[base + 2 * NP4 + g] = r2;
    }
}

extern "C" void kernel_launch(void* const* d_in, const int* in_sizes, int n_in,
                              void* d_out, int out_size, void* d_ws, size_t ws_size,
                              hipStream_t stream) {
    const float* Offset = (const float*)d_in[0];   // (128,3,256,256)
    const float* Posmap = (const float*)d_in[1];   // (128,3,256,256)
    const float* meanp  = (const float*)d_in[2];   // (3,256,256)
    const int*   uv     = (const int*)d_in[3];     // (68,2)
    float* out = (float*)d_out;

    dim3 grid(NP4 / 256, NBATCH / KB);
    fused_rebuild_kernel<<<grid, 256, 0, stream>>>(
        Offset, Posmap, meanp, uv,
        (const f32x4*)Offset, (const f32x4*)meanp, (f32x4*)out);
}

// Round 7
// 43.831 us; speedup vs baseline: 1.1138x; 1.1138x over previous
//
#include <hip/hip_runtime.h>
#include <math.h>

#define HW 256
#define NPTS (HW * HW)
#define NP4 (NPTS / 4)
#define NKPT 68
#define NBATCH 128

typedef float f32x4 __attribute__((ext_vector_type(4)));

// ---------------------------------------------------------------------------
// Kernel 1: per-batch similarity transform (one block of 128 threads per batch).
// Threads 0..67 gather keypoints and compute per-point terms; 17 scalars are
// wave-reduced (shfl) + combined across the 2 waves in LDS. Thread 0 then does
// the 3x3 polar decomposition in fp32 via Newton iteration
//   X <- 0.5*(X + X^-T),  X^-T = cof(X)/det(X).
// R = V U^T from SVD(H) == polar factor of H^T; invariant to positive scale,
// so H is built WITHOUT the s factor: H = sum(src*dst^T) - N*mSrc*mDst^T.
// Output per batch: 12 floats = [ (s*R)[0..8] row-major , t[0..2] ].
// ---------------------------------------------------------------------------
__global__ __launch_bounds__(128) void kpt_tform_kernel(
    const float* __restrict__ Offset,   // (B,3,HW,HW)
    const float* __restrict__ Posmap,   // (B,3,HW,HW)
    const float* __restrict__ meanp,    // (3,HW,HW)
    const int*   __restrict__ uv,       // (68,2)
    float* __restrict__ Rt)             // (B,12)
{
    const int b    = blockIdx.x;
    const int i    = threadIdx.x;
    const int wave = i >> 6;
    const int lane = i & 63;

    __shared__ float s0[6];            // src0[3], dst0[3]
    __shared__ float partial[2][17];

    float src[3] = {0.f, 0.f, 0.f};
    float dst[3] = {0.f, 0.f, 0.f};

    if (i < NKPT) {
        const int u = uv[2 * i + 0];
        const int v = uv[2 * i + 1];
        const int pix = u * HW + v;
        const float* ob = Offset + (size_t)b * 3 * NPTS;
        const float* pb = Posmap + (size_t)b * 3 * NPTS;
#pragma unroll
        for (int c = 0; c < 3; ++c) {
            src[c] = fmaf(ob[c * NPTS + pix], 6.0f, meanp[c * NPTS + pix]);
            dst[c] = pb[c * NPTS + pix];
        }
    }
    if (i == 0) {
#pragma unroll
        for (int c = 0; c < 3; ++c) { s0[c] = src[c]; s0[3 + c] = dst[c]; }
    }
    __syncthreads();

    float vals[17];
    float d1 = 0.f, d2 = 0.f;
    if (i >= 1 && i < NKPT) {
        float dx = src[0] - s0[0], dy = src[1] - s0[1], dz = src[2] - s0[2];
        d1 = sqrtf(dx * dx + dy * dy + dz * dz);
        dx = dst[0] - s0[3]; dy = dst[1] - s0[4]; dz = dst[2] - s0[5];
        d2 = sqrtf(dx * dx + dy * dy + dz * dz);
    }
    vals[0] = d1;
    vals[1] = d2;
#pragma unroll
    for (int c = 0; c < 3; ++c) { vals[2 + c] = src[c]; vals[5 + c] = dst[c]; }
#pragma unroll
    for (int r = 0; r < 3; ++r)
#pragma unroll
        for (int c = 0; c < 3; ++c)
            vals[8 + r * 3 + c] = src[r] * dst[c];

#pragma unroll
    for (int j = 0; j < 17; ++j) {
        float v = vals[j];
#pragma unroll
        for (int off = 32; off > 0; off >>= 1)
            v += __shfl_down(v, off);
        if (lane == 0) partial[wave][j] = v;
    }
    __syncthreads();
    if (i != 0) return;

    float sum[17];
#pragma unroll
    for (int j = 0; j < 17; ++j) sum[j] = partial[0][j] + partial[1][j];

    const float s = sum[1] / sum[0];
    const float invN = 1.0f / (float)NKPT;
    float mS[3], mD[3];
#pragma unroll
    for (int c = 0; c < 3; ++c) { mS[c] = sum[2 + c] * invN; mD[c] = sum[5 + c] * invN; }

    float Hm[3][3];
#pragma unroll
    for (int r = 0; r < 3; ++r)
#pragma unroll
        for (int c = 0; c < 3; ++c)
            Hm[r][c] = sum[8 + r * 3 + c] - (float)NKPT * mS[r] * mD[c];

    float X[3][3];
#pragma unroll
    for (int r = 0; r < 3; ++r)
#pragma unroll
        for (int c = 0; c < 3; ++c)
            X[r][c] = Hm[c][r];

    float nf = 0.f;
#pragma unroll
    for (int r = 0; r < 3; ++r)
#pragma unroll
        for (int c = 0; c < 3; ++c)
            nf += X[r][c] * X[r][c];
    nf = rsqrtf(nf);
#pragma unroll
    for (int r = 0; r < 3; ++r)
#pragma unroll
        for (int c = 0; c < 3; ++c)
            X[r][c] *= nf;

    for (int it = 0; it < 20; ++it) {
        float C[3][3];
        C[0][0] = X[1][1] * X[2][2] - X[1][2] * X[2][1];
        C[0][1] = X[1][2] * X[2][0] - X[1][0] * X[2][2];
        C[0][2] = X[1][0] * X[2][1] - X[1][1] * X[2][0];
        C[1][0] = X[2][1] * X[0][2] - X[2][2] * X[0][1];
        C[1][1] = X[2][2] * X[0][0] - X[2][0] * X[0][2];
        C[1][2] = X[2][0] * X[0][1] - X[2][1] * X[0][0];
        C[2][0] = X[0][1] * X[1][2] - X[0][2] * X[1][1];
        C[2][1] = X[0][2] * X[1][0] - X[0][0] * X[1][2];
        C[2][2] = X[0][0] * X[1][1] - X[0][1] * X[1][0];
        const float det = X[0][0] * C[0][0] + X[0][1] * C[0][1] + X[0][2] * C[0][2];
        const float inv = 0.5f / det;
#pragma unroll
        for (int r = 0; r < 3; ++r)
#pragma unroll
            for (int c = 0; c < 3; ++c)
                X[r][c] = 0.5f * X[r][c] + C[r][c] * inv;
    }

    float* o = Rt + b * 12;
#pragma unroll
    for (int r = 0; r < 3; ++r) {
#pragma unroll
        for (int c = 0; c < 3; ++c)
            o[r * 3 + c] = s * X[r][c];
        o[9 + r] = mD[r] - s * (X[r][0] * mS[0] + X[r][1] * mS[1] + X[r][2] * mS[2]);
    }
}

// ---------------------------------------------------------------------------
// Kernel 2: out[b,r,i] = sum_c (s*R)[r][c] * (Offset[b,c,i]*6 + mean[c,i]) + t[r]
// float4-vectorized streaming pass; nontemporal stores (output never re-read).
// Exact round-2 configuration — measured best (43.80 us total). Isolated
// variables since, all neutral or regressive: MLP depth, plain stores, KB=4
// mean reuse, full fusion. Runs at ~82% of the 2-stream copy ceiling with an
// inherent 7-stream read/write mix.
// ---------------------------------------------------------------------------
__global__ __launch_bounds__(256) void apply_tform_kernel(
    const f32x4* __restrict__ Off,      // (B,3,NP4)
    const f32x4* __restrict__ meanp,    // (3,NP4)
    const float* __restrict__ Rt,       // (B,12)
    f32x4* __restrict__ out)            // (B,3,NP4)
{
    const int b = blockIdx.y;
    const int g = blockIdx.x * blockDim.x + threadIdx.x;   // pixel-group index

    __shared__ float srt[12];
    if (threadIdx.x < 12) srt[threadIdx.x] = Rt[b * 12 + threadIdx.x];
    __syncthreads();

    const float R00 = srt[0], R01 = srt[1], R02 = srt[2];
    const float R10 = srt[3], R11 = srt[4], R12 = srt[5];
    const float R20 = srt[6], R21 = srt[7], R22 = srt[8];
    const float t0 = srt[9], t1 = srt[10], t2 = srt[11];

    const size_t base = (size_t)b * 3 * NP4;
    const f32x4 ox = Off[base + 0 * NP4 + g];
    const f32x4 oy = Off[base + 1 * NP4 + g];
    const f32x4 oz = Off[base + 2 * NP4 + g];
    const f32x4 mx = meanp[0 * NP4 + g];
    const f32x4 my = meanp[1 * NP4 + g];
    const f32x4 mz = meanp[2 * NP4 + g];

    f32x4 r0, r1, r2;
#pragma unroll
    for (int j = 0; j < 4; ++j) {
        const float px = fmaf(ox[j], 6.0f, mx[j]);
        const float py = fmaf(oy[j], 6.0f, my[j]);
        const float pz = fmaf(oz[j], 6.0f, mz[j]);
        r0[j] = fmaf(R00, px, fmaf(R01, py, fmaf(R02, pz, t0)));
        r1[j] = fmaf(R10, px, fmaf(R11, py, fmaf(R12, pz, t1)));
        r2[j] = fmaf(R20, px, fmaf(R21, py, fmaf(R22, pz, t2)));
    }

    __builtin_nontemporal_store(r0, &out[base + 0 * NP4 + g]);
    __builtin_nontemporal_store(r1, &out[base + 1 * NP4 + g]);
    __builtin_nontemporal_store(r2, &out[base + 2 * NP4 + g]);
}

extern "C" void kernel_launch(void* const* d_in, const int* in_sizes, int n_in,
                              void* d_out, int out_size, void* d_ws, size_t ws_size,
                              hipStream_t stream) {
    const float* Offset = (const float*)d_in[0];   // (128,3,256,256)
    const float* Posmap = (const float*)d_in[1];   // (128,3,256,256)
    const float* meanp  = (const float*)d_in[2];   // (3,256,256)
    const int*   uv     = (const int*)d_in[3];     // (68,2)
    float* out = (float*)d_out;
    float* Rt  = (float*)d_ws;                     // 128*12 floats

    kpt_tform_kernel<<<NBATCH, 128, 0, stream>>>(Offset, Posmap, meanp, uv, Rt);

    dim3 grid(NP4 / 256, NBATCH);
    apply_tform_kernel<<<grid, 256, 0, stream>>>(
        (const f32x4*)Offset, (const f32x4*)meanp, Rt, (f32x4*)out);
}